// Round 10
// baseline (409.220 us; speedup 1.0000x reference)
//
#include <hip/hip_runtime.h>
#include <stdint.h>

// Problem constants: B=16, C=48, H=W=64, N_CORR=2048
#define BB 16
#define HW 4096
#define NC 2048
#define KB 96            // bytes per column of data (48 bf16)
#define GRPB 12288       // bytes per 128-col group: [6 chunks][128 cols][16B]
#define IMGB 393216      // bytes per (img,b) image: 32 groups

typedef __attribute__((ext_vector_type(8))) __bf16 bf16x8;
typedef __attribute__((ext_vector_type(8))) short short8;
typedef __attribute__((ext_vector_type(4))) float floatx4;
typedef __attribute__((ext_vector_type(16))) float floatx16;

static __device__ __forceinline__ unsigned short f2bf(float f) {
    unsigned u = __builtin_bit_cast(unsigned, f);
    unsigned r = u + 0x7fffu + ((u >> 16) & 1u);    // RNE
    return (unsigned short)(r >> 16);
}

#define GLD16(g, l) __builtin_amdgcn_global_load_lds((const __attribute__((address_space(1))) void*)(g), (__attribute__((address_space(3))) void*)(l), 16, 0, 0)

// ---------------------------------------------------------------------------
// prep_fused (R16 form + done-counter zero): dbp stored TILE-K-MAJOR:
// per (img,b), 32 groups of [chunk k 0..5][col c 0..127][16B].
// ---------------------------------------------------------------------------
__global__ void prep_fused(const float* __restrict__ x1, const float* __restrict__ x2,
                           const int* __restrict__ ids, const int* __restrict__ fp2,
                           unsigned short* __restrict__ dbp,
                           int* __restrict__ perm, int* __restrict__ qcol_s,
                           int* __restrict__ aqpack, unsigned int* __restrict__ maxs2enc,
                           unsigned int* __restrict__ done) {
    __shared__ __align__(16) unsigned char slab[24576 + 4096 + 1024];
    int bid = blockIdx.x, tid = threadIdx.x;
    if (bid < 512) {
        int img = bid >> 8;
        int b = (bid >> 4) & 15;
        int p0 = (bid & 15) * 256;
        int w = tid >> 6, l = tid & 63;
        const float* x = img ? x2 : x1;
        const float* base = x + ((size_t)b * 48 + w * 12) * HW + p0 + 4 * l;
        floatx4 v[12];
        floatx4 ps = {0.f, 0.f, 0.f, 0.f};
#pragma unroll
        for (int cc = 0; cc < 12; ++cc) {
            v[cc] = *(const floatx4*)(base + cc * HW);
#pragma unroll
            for (int q = 0; q < 4; ++q) ps[q] = fmaf(v[cc][q], v[cc][q], ps[q]);
        }
        float* psum = (float*)(slab + 24576);             // [4 waves][256 cols]
        float* rbuf = (float*)(slab + 24576 + 4096);      // [256 cols]
        *(floatx4*)(psum + w * 256 + 4 * l) = ps;
        __syncthreads();
        float s = psum[tid] + psum[256 + tid] + psum[512 + tid] + psum[768 + tid];
        rbuf[tid] = 1.f / fmaxf(sqrtf(s), 1e-12f);
        __syncthreads();
        floatx4 rv = *(const floatx4*)(rbuf + 4 * l);
#pragma unroll
        for (int q = 0; q < 4; ++q) {
            unsigned u[6];
#pragma unroll
            for (int p = 0; p < 6; ++p) {
                u[p] = (unsigned)f2bf(v[2 * p][q] * rv[q]) |
                       ((unsigned)f2bf(v[2 * p + 1][q] * rv[q]) << 16);
            }
            unsigned char* dst = slab + (4 * l + q) * KB + w * 24;  // 8-aligned
            *(uint2*)(dst + 0)  = make_uint2(u[0], u[1]);
            *(uint2*)(dst + 8)  = make_uint2(u[2], u[3]);
            *(uint2*)(dst + 16) = make_uint2(u[4], u[5]);
        }
        __syncthreads();
        // write-out: remap col-major slab -> tile-K-major global, coalesced
        unsigned char* dstb = (unsigned char*)dbp + (size_t)(img * BB + b) * IMGB
                              + (p0 >> 7) * GRPB;
#pragma unroll
        for (int i = 0; i < 6; ++i) {                     // 2 groups * 12288 B
            int L = i * 4096 + tid * 16;
            int g = L / GRPB;                             // 0..1
            int r = L - g * GRPB;
            int k = r >> 11;                              // chunk 0..5
            int c = (r & 2047) >> 4;                      // col 0..127
            *(floatx4*)(dstb + L) = *(const floatx4*)(slab + (g * 128 + c) * KB + k * 16);
        }
    } else if (bid < 544) {
        int* hist = (int*)slab;
        int* base = hist + 64;
        int seg = bid - 512;                      // dir*16 + b
        int dir = seg >> 4, b = seg & 15;
        if (tid < 64) hist[tid] = 0;
        __syncthreads();
#pragma unroll
        for (int k = 0; k < 8; ++k) {
            int n = k * 256 + tid;
            int idv = ids[b * NC + n];
            int i2 = fp2[b * 2 * NC + n];
            int qi = (dir == 0) ? i2 : (idv >> 6);
            atomicAdd(&hist[qi], 1);
        }
        __syncthreads();
        if (tid == 0) {
            int run = 0;
            for (int k = 0; k < 64; ++k) { base[k] = run; run += hist[k]; }
        }
        __syncthreads();
#pragma unroll
        for (int k = 0; k < 8; ++k) {
            int n = k * 256 + tid;
            int idv = ids[b * NC + n];
            int i2 = fp2[b * 2 * NC + n];
            int j2 = fp2[b * 2 * NC + NC + n];
            int qi, qj, qcol;
            if (dir == 0) { qi = i2; qj = j2; qcol = idv; }
            else          { qi = idv >> 6; qj = idv & 63; qcol = i2 * 64 + j2; }
            int slot = atomicAdd(&base[qi], 1);
            perm[seg * NC + slot] = n;
            qcol_s[seg * NC + slot] = qcol;
            aqpack[seg * NC + slot] = (qi << 8) | qj;
        }
    } else {
        int t = (bid - 544) * 256 + tid;          // [0, 2048)
        uint4* p = (uint4*)maxs2enc;              // 16384 uint4 total
        uint4 z = {0u, 0u, 0u, 0u};
#pragma unroll
        for (int k = 0; k < 8; ++k) p[k * 2048 + t] = z;
        if (t == 0) done[0] = 0u;                 // loss tail-block ticket
    }
}

// ---------------------------------------------------------------------------
// maxscore_mfma (R21): 32x32x16 bf16 MFMA — K=48 NATIVE (3 x K16, no pad).
// Arithmetic: per 32q x 32col x K48 block, 3 MFMA x 8 cyc = 24 cyc vs the
// 16x16x32 path's 8 MFMA x 5 cyc = 40 cyc (25% of which multiplied zeros).
// 1.67x less matrix-pipe time, 25% fewer ds_read_b128 (12 vs 16/tile/wave),
// and the zero-A-quad hack disappears.  Layouts (guide-verified m74/m101):
// A/B: row|col = lane&31, k = 8*(lane>>5)+j; C/D: col = lane&31,
// row = (reg&3)+8*(reg>>2)+4*(lane>>5).  Anchors packed 2x16b per VGPR;
// mask epilogue = unsigned-range integer tests (active path only, ~20%).
// Kept: tile-K-major dbp, LDS dbuf via global_load_lds (R18: direct L2
// reads regressed), R17 strided group walk g=tile*4+nq (balance),
// launch_bounds(256,4) (R13 spill lesson), grid 1024 (256 q/block).
// Peak VGPR ~112 < 128 cap.
// ---------------------------------------------------------------------------
#define TILEB 12288      // [6][128][16B] == GRPB

static __device__ __forceinline__ void dma_tile(const unsigned char* g, unsigned char* l,
                                                int wave, int lane) {
#pragma unroll
    for (int rr = 0; rr < 3; ++rr)
        GLD16(g + rr * 4096 + wave * 1024 + lane * 16, l + rr * 4096 + wave * 1024);
}

__global__ __launch_bounds__(256, 4) void maxscore_mfma(
    const unsigned short* __restrict__ dbp,
    const int* __restrict__ perm, const int* __restrict__ qcol_s,
    const int* __restrict__ aqpack, unsigned int* __restrict__ maxs2enc) {
    __shared__ __align__(16) unsigned char smem[2 * TILEB];  // 24576 B

    int tid = threadIdx.x, wave = tid >> 6, lane = tid & 63;
    int hi = lane >> 5, lo = lane & 31;
    int gid = blockIdx.x;
    int seg = gid & 31, dir = seg >> 4, b = seg & 15;
    int rest = gid >> 5, mtile = rest & 7, nq = rest >> 3;   // nq in [0,4)
    int qbase = mtile * 256;
    int dbimg = 1 - dir;
    int segb = seg * NC;

    // A-fragments: row = lane&31 (query slot), k = 8*hi + j per K16 step ks:
    // chunk = 2*ks + hi in the tile-K-major column. 6 chunks = all 48 k. No pad.
    const unsigned char* dbQ = (const unsigned char*)dbp + (size_t)(dir * BB + b) * IMGB;
    short8 afr[2][3];
#pragma unroll
    for (int trow = 0; trow < 2; ++trow) {
        int slot = qbase + wave * 64 + trow * 32 + lo;
        int qc = qcol_s[segb + slot];
        const unsigned char* src = dbQ + (qc >> 7) * GRPB + (qc & 127) * 16;
#pragma unroll
        for (int ks = 0; ks < 3; ++ks)
            afr[trow][ks] = *(const short8*)(src + (2 * ks + hi) * 2048);
    }
    // Packed anchors: app[trow][p] = aq(2p) | aq(2p+1)<<16 for this lane's
    // C/D rows row(r) = (r&3)+8*(r>>2)+4*hi  (aq = (qi<<8)|qj, 16-bit)
    int app[2][8];
#pragma unroll
    for (int trow = 0; trow < 2; ++trow)
#pragma unroll
        for (int p = 0; p < 8; ++p) {
            int r0 = 2 * p, r1 = r0 + 1;
            int row0 = (r0 & 3) + 8 * (r0 >> 2) + 4 * hi;
            int row1 = (r1 & 3) + 8 * (r1 >> 2) + 4 * hi;
            int s0 = aqpack[segb + qbase + wave * 64 + trow * 32 + row0];
            int s1 = aqpack[segb + qbase + wave * 64 + trow * 32 + row1];
            app[trow][p] = (s0 & 0xffff) | (s1 << 16);
        }
    // Wave's sorted qi range (64 consecutive sorted slots)
    int wb = segb + qbase + wave * 64;
    int qimin = __builtin_amdgcn_readfirstlane(aqpack[wb] >> 8);
    int qimax = __builtin_amdgcn_readfirstlane(aqpack[wb + 63] >> 8);

    const unsigned char* dbase = (const unsigned char*)dbp + (size_t)(dbimg * BB + b) * IMGB;
    dma_tile(dbase + (size_t)nq * GRPB, smem, wave, lane);   // prefetch g = nq

    floatx16 zf16;
#pragma unroll
    for (int r = 0; r < 16; ++r) zf16[r] = 0.f;
    float mx[2][16];
#pragma unroll
    for (int trow = 0; trow < 2; ++trow)
#pragma unroll
        for (int r = 0; r < 16; ++r) mx[trow][r] = -1e30f;

    for (int tile = 0; tile < 8; ++tile) {
        unsigned char* buf = smem + (tile & 1) * TILEB;
        __syncthreads();
        if (tile + 1 < 8)
            dma_tile(dbase + (size_t)((tile + 1) * 4 + nq) * GRPB,
                     smem + ((tile + 1) & 1) * TILEB, wave, lane);
        int g = tile * 4 + nq;
#pragma unroll
        for (int cb = 0; cb < 4; ++cb) {                  // 32-col blocks
            int mi = 2 * g + (cb >> 1);
            bool active = (mi >= qimin - 4) && (mi <= qimax + 4);   // wave-uniform
            short8 bfr[3];
#pragma unroll
            for (int ks = 0; ks < 3; ++ks)
                bfr[ks] = *(const short8*)(buf + (2 * ks + hi) * 2048 + (cb * 32 + lo) * 16);
            if (active) {
                int jc = (cb & 1) * 32 + lo;              // j-coordinate of this col
#pragma unroll
                for (int trow = 0; trow < 2; ++trow) {
                    floatx16 acc = __builtin_amdgcn_mfma_f32_32x32x16_bf16(
                        __builtin_bit_cast(bf16x8, afr[trow][0]),
                        __builtin_bit_cast(bf16x8, bfr[0]), zf16, 0, 0, 0);
                    acc = __builtin_amdgcn_mfma_f32_32x32x16_bf16(
                        __builtin_bit_cast(bf16x8, afr[trow][1]),
                        __builtin_bit_cast(bf16x8, bfr[1]), acc, 0, 0, 0);
                    acc = __builtin_amdgcn_mfma_f32_32x32x16_bf16(
                        __builtin_bit_cast(bf16x8, afr[trow][2]),
                        __builtin_bit_cast(bf16x8, bfr[2]), acc, 0, 0, 0);
#pragma unroll
                    for (int r = 0; r < 16; ++r) {
                        int pk = app[trow][r >> 1];
                        int qi = (r & 1) ? ((pk >> 24) & 255) : ((pk >> 8) & 255);
                        int qj = (r & 1) ? ((pk >> 16) & 255) : (pk & 255);
                        bool ok = ((unsigned)(qi - mi + 4) > 8u) |
                                  ((unsigned)(qj - jc + 4) > 8u);
                        mx[trow][r] = ok ? fmaxf(mx[trow][r], acc[r]) : mx[trow][r];
                    }
                }
            } else {                                      // all rows allowed
#pragma unroll
                for (int trow = 0; trow < 2; ++trow) {
                    floatx16 acc = __builtin_amdgcn_mfma_f32_32x32x16_bf16(
                        __builtin_bit_cast(bf16x8, afr[trow][0]),
                        __builtin_bit_cast(bf16x8, bfr[0]), zf16, 0, 0, 0);
                    acc = __builtin_amdgcn_mfma_f32_32x32x16_bf16(
                        __builtin_bit_cast(bf16x8, afr[trow][1]),
                        __builtin_bit_cast(bf16x8, bfr[1]), acc, 0, 0, 0);
                    acc = __builtin_amdgcn_mfma_f32_32x32x16_bf16(
                        __builtin_bit_cast(bf16x8, afr[trow][2]),
                        __builtin_bit_cast(bf16x8, bfr[2]), acc, 0, 0, 0);
#pragma unroll
                    for (int r = 0; r < 16; ++r)
                        mx[trow][r] = fmaxf(mx[trow][r], acc[r]);
                }
            }
        }
    }

    // reduce max over the 32 lanes (cols) sharing hi
#pragma unroll
    for (int trow = 0; trow < 2; ++trow)
#pragma unroll
        for (int r = 0; r < 16; ++r) {
            float v = mx[trow][r];
            v = fmaxf(v, __shfl_xor(v, 1, 32));
            v = fmaxf(v, __shfl_xor(v, 2, 32));
            v = fmaxf(v, __shfl_xor(v, 4, 32));
            v = fmaxf(v, __shfl_xor(v, 8, 32));
            v = fmaxf(v, __shfl_xor(v, 16, 32));
            mx[trow][r] = v;
        }
    if (lo == 0) {                                        // 2 writer lanes/wave
#pragma unroll
        for (int trow = 0; trow < 2; ++trow)
#pragma unroll
            for (int r = 0; r < 16; ++r) {
                int row = (r & 3) + 8 * (r >> 2) + 4 * hi;
                int slot = qbase + wave * 64 + trow * 32 + row;
                int orig = perm[segb + slot];
                float v = mx[trow][r] + 2.0f;             // > 0: uint-monotone
                atomicMax(&maxs2enc[(size_t)segb + orig],
                          __builtin_bit_cast(unsigned, v));
            }
    }
}

// ---------------------------------------------------------------------------
// loss (R19): pos-distance from tile-K-major dbp bf16 columns, decode/merge
// the two direction maxes, weighted partials — PLUS the former final_kernel,
// executed by the last block to finish (device-scope atomicAdd ticket +
// __threadfence, Guideline-16 pattern).  grid = 128.
// ---------------------------------------------------------------------------
__global__ void loss_kernel(const float* __restrict__ att1, const float* __restrict__ att2,
                            const int* __restrict__ ids, const int* __restrict__ fp2,
                            const unsigned short* __restrict__ dbp,
                            const unsigned int* __restrict__ maxs2enc,
                            float* __restrict__ pnum, float* __restrict__ pden,
                            unsigned int* __restrict__ done, float* __restrict__ out) {
    int b = blockIdx.x >> 3, chunk = blockIdx.x & 7;
    int tid = threadIdx.x;
    int n = chunk * 256 + tid;
    int idv = ids[b * NC + n];
    int i2 = fp2[b * 2 * NC + n], j2 = fp2[b * 2 * NC + NC + n];
    int c2 = i2 * 64 + j2;
    const unsigned char* a4 = (const unsigned char*)dbp + (size_t)(0 * BB + b) * IMGB
                              + (idv >> 7) * GRPB + (idv & 127) * 16;
    const unsigned char* b4 = (const unsigned char*)dbp + (size_t)(1 * BB + b) * IMGB
                              + (c2 >> 7) * GRPB + (c2 & 127) * 16;
    float dot = 0.f;
#pragma unroll
    for (int i = 0; i < 6; ++i) {                         // 6 chunks x 16 B
        uint4 xa = *(const uint4*)(a4 + i * 2048);
        uint4 xb = *(const uint4*)(b4 + i * 2048);
        const unsigned* xu = (const unsigned*)&xa;
        const unsigned* yu = (const unsigned*)&xb;
#pragma unroll
        for (int w = 0; w < 4; ++w) {
            float xl = __builtin_bit_cast(float, xu[w] << 16);
            float xh = __builtin_bit_cast(float, xu[w] & 0xffff0000u);
            float yl = __builtin_bit_cast(float, yu[w] << 16);
            float yh = __builtin_bit_cast(float, yu[w] & 0xffff0000u);
            dot = fmaf(xl, yl, fmaf(xh, yh, dot));
        }
    }
    float m0 = __builtin_bit_cast(float, maxs2enc[(size_t)(0 * BB + b) * NC + n]) - 2.0f;
    float m1 = __builtin_bit_cast(float, maxs2enc[(size_t)(1 * BB + b) * NC + n]) - 2.0f;
    float ms = fmaxf(m0, m1);
    float diff = (2.f - 2.f * dot) - (2.f - 2.f * ms);
    float w = att1[b * HW + idv] * att2[b * HW + c2];
    float num = w * fmaxf(0.f, 1.f + diff);
    float den = w;
    __shared__ float sn[256], sd[256];
    __shared__ int islast;
    sn[tid] = num; sd[tid] = den;
    __syncthreads();
    for (int s = 128; s > 0; s >>= 1) {
        if (tid < s) { sn[tid] += sn[tid + s]; sd[tid] += sd[tid + s]; }
        __syncthreads();
    }
    if (tid == 0) {
        pnum[blockIdx.x] = sn[0];
        pden[blockIdx.x] = sd[0];
        __threadfence();                                  // release partials
        unsigned t = atomicAdd(done, 1u);
        islast = (t == 127u);
    }
    __syncthreads();
    if (islast) {
        __threadfence();                                  // acquire partials
        if (tid < 16) {
            float nacc = 0.f, dacc = 0.f;
#pragma unroll
            for (int c = 0; c < 8; ++c) {
                nacc += pnum[tid * 8 + c];
                dacc += pden[tid * 8 + c];
            }
            sn[tid] = nacc / dacc;
        }
        __syncthreads();
        if (tid == 0) {
            float s = 0.f;
#pragma unroll
            for (int k = 0; k < 16; ++k) s += sn[k];
            out[0] = s * (1.f / BB);
        }
    }
}

extern "C" void kernel_launch(void* const* d_in, const int* in_sizes, int n_in,
                              void* d_out, int out_size, void* d_ws, size_t ws_size,
                              hipStream_t stream) {
    const float* x1  = (const float*)d_in[0];
    const float* x2  = (const float*)d_in[1];
    const float* att1 = (const float*)d_in[2];
    const float* att2 = (const float*)d_in[3];
    const int* ids   = (const int*)d_in[4];
    const int* fp2   = (const int*)d_in[5];
    float* out = (float*)d_out;

    // ws layout (bytes), ~13.6 MB. (R8 finding: the harness poisons the FULL
    // d_ws allocation every iteration (~44 us) regardless of use.)
    unsigned char* w = (unsigned char*)d_ws;
    unsigned short* dbp = (unsigned short*)(w + 0);          // 2*16*393216 = 12,582,912
    int* perm    = (int*)(w + 12582912);                     // 32*2048*4 = 262,144
    int* qcol_s  = (int*)(w + 12845056);                     // 262,144
    int* aqpack  = (int*)(w + 13107200);                     // 262,144
    unsigned int* maxs2enc = (unsigned int*)(w + 13369344);  // 262,144
    float* pnum  = (float*)(w + 13631488);                   // 512
    float* pden  = (float*)(w + 13632000);                   // 512
    unsigned int* done = (unsigned int*)(w + 13632512);      // 4

    prep_fused<<<dim3(552), dim3(256), 0, stream>>>(x1, x2, ids, fp2, dbp,
                                                    perm, qcol_s, aqpack, maxs2enc, done);
    maxscore_mfma<<<dim3(1024), dim3(256), 0, stream>>>(dbp, perm, qcol_s, aqpack, maxs2enc);
    loss_kernel<<<dim3(128), dim3(256), 0, stream>>>(att1, att2, ids, fp2, dbp, maxs2enc,
                                                     pnum, pden, done, out);
}

// Round 11
// 147.569 us; speedup vs baseline: 2.7731x; 2.7731x over previous
//
#include <hip/hip_runtime.h>
#include <stdint.h>

// Problem constants: B=16, C=48, H=W=64, N_CORR=2048
#define BB 16
#define HW 4096
#define NC 2048
#define KB 96            // bytes per column of data (48 bf16)
#define GRPB 12288       // bytes per 128-col group: [6 chunks][128 cols][16B]
#define IMGB 393216      // bytes per (img,b) image: 32 groups

typedef __attribute__((ext_vector_type(8))) __bf16 bf16x8;
typedef __attribute__((ext_vector_type(8))) short short8;
typedef __attribute__((ext_vector_type(4))) float floatx4;
typedef __attribute__((ext_vector_type(16))) float floatx16;

static __device__ __forceinline__ unsigned short f2bf(float f) {
    unsigned u = __builtin_bit_cast(unsigned, f);
    unsigned r = u + 0x7fffu + ((u >> 16) & 1u);    // RNE
    return (unsigned short)(r >> 16);
}

#define GLD16(g, l) __builtin_amdgcn_global_load_lds((const __attribute__((address_space(1))) void*)(g), (__attribute__((address_space(3))) void*)(l), 16, 0, 0)

// ---------------------------------------------------------------------------
// prep_fused (R16 form + done-counter zero): dbp stored TILE-K-MAJOR:
// per (img,b), 32 groups of [chunk k 0..5][col c 0..127][16B].
// ---------------------------------------------------------------------------
__global__ void prep_fused(const float* __restrict__ x1, const float* __restrict__ x2,
                           const int* __restrict__ ids, const int* __restrict__ fp2,
                           unsigned short* __restrict__ dbp,
                           int* __restrict__ perm, int* __restrict__ qcol_s,
                           int* __restrict__ aqpack, unsigned int* __restrict__ maxs2enc,
                           unsigned int* __restrict__ done) {
    __shared__ __align__(16) unsigned char slab[24576 + 4096 + 1024];
    int bid = blockIdx.x, tid = threadIdx.x;
    if (bid < 512) {
        int img = bid >> 8;
        int b = (bid >> 4) & 15;
        int p0 = (bid & 15) * 256;
        int w = tid >> 6, l = tid & 63;
        const float* x = img ? x2 : x1;
        const float* base = x + ((size_t)b * 48 + w * 12) * HW + p0 + 4 * l;
        floatx4 v[12];
        floatx4 ps = {0.f, 0.f, 0.f, 0.f};
#pragma unroll
        for (int cc = 0; cc < 12; ++cc) {
            v[cc] = *(const floatx4*)(base + cc * HW);
#pragma unroll
            for (int q = 0; q < 4; ++q) ps[q] = fmaf(v[cc][q], v[cc][q], ps[q]);
        }
        float* psum = (float*)(slab + 24576);             // [4 waves][256 cols]
        float* rbuf = (float*)(slab + 24576 + 4096);      // [256 cols]
        *(floatx4*)(psum + w * 256 + 4 * l) = ps;
        __syncthreads();
        float s = psum[tid] + psum[256 + tid] + psum[512 + tid] + psum[768 + tid];
        rbuf[tid] = 1.f / fmaxf(sqrtf(s), 1e-12f);
        __syncthreads();
        floatx4 rv = *(const floatx4*)(rbuf + 4 * l);
#pragma unroll
        for (int q = 0; q < 4; ++q) {
            unsigned u[6];
#pragma unroll
            for (int p = 0; p < 6; ++p) {
                u[p] = (unsigned)f2bf(v[2 * p][q] * rv[q]) |
                       ((unsigned)f2bf(v[2 * p + 1][q] * rv[q]) << 16);
            }
            unsigned char* dst = slab + (4 * l + q) * KB + w * 24;  // 8-aligned
            *(uint2*)(dst + 0)  = make_uint2(u[0], u[1]);
            *(uint2*)(dst + 8)  = make_uint2(u[2], u[3]);
            *(uint2*)(dst + 16) = make_uint2(u[4], u[5]);
        }
        __syncthreads();
        // write-out: remap col-major slab -> tile-K-major global, coalesced
        unsigned char* dstb = (unsigned char*)dbp + (size_t)(img * BB + b) * IMGB
                              + (p0 >> 7) * GRPB;
#pragma unroll
        for (int i = 0; i < 6; ++i) {                     // 2 groups * 12288 B
            int L = i * 4096 + tid * 16;
            int g = L / GRPB;                             // 0..1
            int r = L - g * GRPB;
            int k = r >> 11;                              // chunk 0..5
            int c = (r & 2047) >> 4;                      // col 0..127
            *(floatx4*)(dstb + L) = *(const floatx4*)(slab + (g * 128 + c) * KB + k * 16);
        }
    } else if (bid < 544) {
        int* hist = (int*)slab;
        int* base = hist + 64;
        int seg = bid - 512;                      // dir*16 + b
        int dir = seg >> 4, b = seg & 15;
        if (tid < 64) hist[tid] = 0;
        __syncthreads();
#pragma unroll
        for (int k = 0; k < 8; ++k) {
            int n = k * 256 + tid;
            int idv = ids[b * NC + n];
            int i2 = fp2[b * 2 * NC + n];
            int qi = (dir == 0) ? i2 : (idv >> 6);
            atomicAdd(&hist[qi], 1);
        }
        __syncthreads();
        if (tid == 0) {
            int run = 0;
            for (int k = 0; k < 64; ++k) { base[k] = run; run += hist[k]; }
        }
        __syncthreads();
#pragma unroll
        for (int k = 0; k < 8; ++k) {
            int n = k * 256 + tid;
            int idv = ids[b * NC + n];
            int i2 = fp2[b * 2 * NC + n];
            int j2 = fp2[b * 2 * NC + NC + n];
            int qi, qj, qcol;
            if (dir == 0) { qi = i2; qj = j2; qcol = idv; }
            else          { qi = idv >> 6; qj = idv & 63; qcol = i2 * 64 + j2; }
            int slot = atomicAdd(&base[qi], 1);
            perm[seg * NC + slot] = n;
            qcol_s[seg * NC + slot] = qcol;
            aqpack[seg * NC + slot] = (qi << 8) | qj;
        }
    } else {
        int t = (bid - 544) * 256 + tid;          // [0, 2048)
        uint4* p = (uint4*)maxs2enc;              // 16384 uint4 total
        uint4 z = {0u, 0u, 0u, 0u};
#pragma unroll
        for (int k = 0; k < 8; ++k) p[k * 2048 + t] = z;
        if (t == 0) done[0] = 0u;                 // loss tail-block ticket
    }
}

// ---------------------------------------------------------------------------
// maxscore_mfma (R22): 32x32x16 bf16 MFMA, SLIMMED — one 32-query row per
// wave.  R21 post-mortem: mechanism correct (passed, absmax 0) but the
// floatx16 accumulators pushed the unified-file AGPR split past budget ->
// VGPR side capped at 64, afr/app/mx spilled (FETCH 582 MB, 320 us).
// Slim state: afr[3]=12 VGPR, app[8]=8, mx[16]=16, acc+zf ~32 AGPR-side,
// bfr[3]=12 transient -> peak ~80 total, no spill.  Per tile per wave:
// 12 ds_read_b128 + 12 MFMA x 8 cyc = 96 cyc matrix-pipe vs the 16x16x32
// t=2 form's 16 reads + 32 MFMA x 5 = 160 cyc (K=48 native, no zero pad).
// Geometry = measured-good R16/R17: grid 2048 = 32 seg x 16 mtile x 4 nq,
// 128 q/block, strided walk g = tile*4 + nq (uniform block cost).
// Kept: tile-K-major dbp, LDS dbuf (R18: direct L2 reads regressed),
// launch_bounds(256,4) (R13), fused loss (R19).
// Layouts (verified by R21's pass): A/B row|col = lane&31, k = 16ks+8hi+j
// -> chunk 2ks+hi; C/D col = lane&31, row = (r&3)+8*(r>>2)+4*hi (m74/m101).
// ---------------------------------------------------------------------------
#define TILEB 12288      // [6][128][16B] == GRPB

static __device__ __forceinline__ void dma_tile(const unsigned char* g, unsigned char* l,
                                                int wave, int lane) {
#pragma unroll
    for (int rr = 0; rr < 3; ++rr)
        GLD16(g + rr * 4096 + wave * 1024 + lane * 16, l + rr * 4096 + wave * 1024);
}

__global__ __launch_bounds__(256, 4) void maxscore_mfma(
    const unsigned short* __restrict__ dbp,
    const int* __restrict__ perm, const int* __restrict__ qcol_s,
    const int* __restrict__ aqpack, unsigned int* __restrict__ maxs2enc) {
    __shared__ __align__(16) unsigned char smem[2 * TILEB];  // 24576 B

    int tid = threadIdx.x, wave = tid >> 6, lane = tid & 63;
    int hi = lane >> 5, lo = lane & 31;
    int gid = blockIdx.x;
    int seg = gid & 31, dir = seg >> 4, b = seg & 15;
    int rest = gid >> 5, mtile = rest & 15, nq = rest >> 4;  // nq in [0,4)
    int qbase = mtile * 128;
    int dbimg = 1 - dir;
    int segb = seg * NC;

    // A-fragments: row = lane&31 (query slot), K16 step ks -> chunk 2ks+hi.
    const unsigned char* dbQ = (const unsigned char*)dbp + (size_t)(dir * BB + b) * IMGB;
    short8 afr[3];
    {
        int slot = qbase + wave * 32 + lo;
        int qc = qcol_s[segb + slot];
        const unsigned char* src = dbQ + (qc >> 7) * GRPB + (qc & 127) * 16;
#pragma unroll
        for (int ks = 0; ks < 3; ++ks)
            afr[ks] = *(const short8*)(src + (2 * ks + hi) * 2048);
    }
    // Packed anchors: app[p] = aq(2p) | aq(2p+1)<<16 for this lane's C/D
    // rows row(r) = (r&3)+8*(r>>2)+4*hi  (aq = (qi<<8)|qj, 16-bit)
    int app[8];
#pragma unroll
    for (int p = 0; p < 8; ++p) {
        int r0 = 2 * p, r1 = r0 + 1;
        int row0 = (r0 & 3) + 8 * (r0 >> 2) + 4 * hi;
        int row1 = (r1 & 3) + 8 * (r1 >> 2) + 4 * hi;
        int s0 = aqpack[segb + qbase + wave * 32 + row0];
        int s1 = aqpack[segb + qbase + wave * 32 + row1];
        app[p] = (s0 & 0xffff) | (s1 << 16);
    }
    // Wave's sorted qi range (32 consecutive sorted slots)
    int wb = segb + qbase + wave * 32;
    int qimin = __builtin_amdgcn_readfirstlane(aqpack[wb] >> 8);
    int qimax = __builtin_amdgcn_readfirstlane(aqpack[wb + 31] >> 8);

    const unsigned char* dbase = (const unsigned char*)dbp + (size_t)(dbimg * BB + b) * IMGB;
    dma_tile(dbase + (size_t)nq * GRPB, smem, wave, lane);   // prefetch g = nq

    floatx16 zf16;
#pragma unroll
    for (int r = 0; r < 16; ++r) zf16[r] = 0.f;
    float mx[16];
#pragma unroll
    for (int r = 0; r < 16; ++r) mx[r] = -1e30f;

    for (int tile = 0; tile < 8; ++tile) {
        unsigned char* buf = smem + (tile & 1) * TILEB;
        __syncthreads();
        if (tile + 1 < 8)
            dma_tile(dbase + (size_t)((tile + 1) * 4 + nq) * GRPB,
                     smem + ((tile + 1) & 1) * TILEB, wave, lane);
        int g = tile * 4 + nq;
#pragma unroll
        for (int cb = 0; cb < 4; ++cb) {                  // 32-col blocks
            int mi = 2 * g + (cb >> 1);
            bool active = (mi >= qimin - 4) && (mi <= qimax + 4);   // wave-uniform
            short8 bfr[3];
#pragma unroll
            for (int ks = 0; ks < 3; ++ks)
                bfr[ks] = *(const short8*)(buf + (2 * ks + hi) * 2048 + (cb * 32 + lo) * 16);
            floatx16 acc = __builtin_amdgcn_mfma_f32_32x32x16_bf16(
                __builtin_bit_cast(bf16x8, afr[0]),
                __builtin_bit_cast(bf16x8, bfr[0]), zf16, 0, 0, 0);
            acc = __builtin_amdgcn_mfma_f32_32x32x16_bf16(
                __builtin_bit_cast(bf16x8, afr[1]),
                __builtin_bit_cast(bf16x8, bfr[1]), acc, 0, 0, 0);
            acc = __builtin_amdgcn_mfma_f32_32x32x16_bf16(
                __builtin_bit_cast(bf16x8, afr[2]),
                __builtin_bit_cast(bf16x8, bfr[2]), acc, 0, 0, 0);
            if (active) {
                int jc = (cb & 1) * 32 + lo;              // j-coordinate of this col
#pragma unroll
                for (int r = 0; r < 16; ++r) {
                    int pk = app[r >> 1];
                    int qi = (r & 1) ? ((pk >> 24) & 255) : ((pk >> 8) & 255);
                    int qj = (r & 1) ? ((pk >> 16) & 255) : (pk & 255);
                    bool ok = ((unsigned)(qi - mi + 4) > 8u) |
                              ((unsigned)(qj - jc + 4) > 8u);
                    mx[r] = ok ? fmaxf(mx[r], acc[r]) : mx[r];
                }
            } else {                                      // all rows allowed
#pragma unroll
                for (int r = 0; r < 16; ++r)
                    mx[r] = fmaxf(mx[r], acc[r]);
            }
        }
    }

    // reduce max over the 32 lanes (cols) sharing hi
#pragma unroll
    for (int r = 0; r < 16; ++r) {
        float v = mx[r];
        v = fmaxf(v, __shfl_xor(v, 1, 32));
        v = fmaxf(v, __shfl_xor(v, 2, 32));
        v = fmaxf(v, __shfl_xor(v, 4, 32));
        v = fmaxf(v, __shfl_xor(v, 8, 32));
        v = fmaxf(v, __shfl_xor(v, 16, 32));
        mx[r] = v;
    }
    if (lo == 0) {                                        // 2 writer lanes/wave
#pragma unroll
        for (int r = 0; r < 16; ++r) {
            int row = (r & 3) + 8 * (r >> 2) + 4 * hi;
            int slot = qbase + wave * 32 + row;
            int orig = perm[segb + slot];
            float v = mx[r] + 2.0f;                       // > 0: uint-monotone
            atomicMax(&maxs2enc[(size_t)segb + orig],
                      __builtin_bit_cast(unsigned, v));
        }
    }
}

// ---------------------------------------------------------------------------
// loss (R19): pos-distance from tile-K-major dbp bf16 columns, decode/merge
// the two direction maxes, weighted partials — PLUS the former final_kernel,
// executed by the last block to finish (device-scope atomicAdd ticket +
// __threadfence, Guideline-16 pattern).  grid = 128.
// ---------------------------------------------------------------------------
__global__ void loss_kernel(const float* __restrict__ att1, const float* __restrict__ att2,
                            const int* __restrict__ ids, const int* __restrict__ fp2,
                            const unsigned short* __restrict__ dbp,
                            const unsigned int* __restrict__ maxs2enc,
                            float* __restrict__ pnum, float* __restrict__ pden,
                            unsigned int* __restrict__ done, float* __restrict__ out) {
    int b = blockIdx.x >> 3, chunk = blockIdx.x & 7;
    int tid = threadIdx.x;
    int n = chunk * 256 + tid;
    int idv = ids[b * NC + n];
    int i2 = fp2[b * 2 * NC + n], j2 = fp2[b * 2 * NC + NC + n];
    int c2 = i2 * 64 + j2;
    const unsigned char* a4 = (const unsigned char*)dbp + (size_t)(0 * BB + b) * IMGB
                              + (idv >> 7) * GRPB + (idv & 127) * 16;
    const unsigned char* b4 = (const unsigned char*)dbp + (size_t)(1 * BB + b) * IMGB
                              + (c2 >> 7) * GRPB + (c2 & 127) * 16;
    float dot = 0.f;
#pragma unroll
    for (int i = 0; i < 6; ++i) {                         // 6 chunks x 16 B
        uint4 xa = *(const uint4*)(a4 + i * 2048);
        uint4 xb = *(const uint4*)(b4 + i * 2048);
        const unsigned* xu = (const unsigned*)&xa;
        const unsigned* yu = (const unsigned*)&xb;
#pragma unroll
        for (int w = 0; w < 4; ++w) {
            float xl = __builtin_bit_cast(float, xu[w] << 16);
            float xh = __builtin_bit_cast(float, xu[w] & 0xffff0000u);
            float yl = __builtin_bit_cast(float, yu[w] << 16);
            float yh = __builtin_bit_cast(float, yu[w] & 0xffff0000u);
            dot = fmaf(xl, yl, fmaf(xh, yh, dot));
        }
    }
    float m0 = __builtin_bit_cast(float, maxs2enc[(size_t)(0 * BB + b) * NC + n]) - 2.0f;
    float m1 = __builtin_bit_cast(float, maxs2enc[(size_t)(1 * BB + b) * NC + n]) - 2.0f;
    float ms = fmaxf(m0, m1);
    float diff = (2.f - 2.f * dot) - (2.f - 2.f * ms);
    float w = att1[b * HW + idv] * att2[b * HW + c2];
    float num = w * fmaxf(0.f, 1.f + diff);
    float den = w;
    __shared__ float sn[256], sd[256];
    __shared__ int islast;
    sn[tid] = num; sd[tid] = den;
    __syncthreads();
    for (int s = 128; s > 0; s >>= 1) {
        if (tid < s) { sn[tid] += sn[tid + s]; sd[tid] += sd[tid + s]; }
        __syncthreads();
    }
    if (tid == 0) {
        pnum[blockIdx.x] = sn[0];
        pden[blockIdx.x] = sd[0];
        __threadfence();                                  // release partials
        unsigned t = atomicAdd(done, 1u);
        islast = (t == 127u);
    }
    __syncthreads();
    if (islast) {
        __threadfence();                                  // acquire partials
        if (tid < 16) {
            float nacc = 0.f, dacc = 0.f;
#pragma unroll
            for (int c = 0; c < 8; ++c) {
                nacc += pnum[tid * 8 + c];
                dacc += pden[tid * 8 + c];
            }
            sn[tid] = nacc / dacc;
        }
        __syncthreads();
        if (tid == 0) {
            float s = 0.f;
#pragma unroll
            for (int k = 0; k < 16; ++k) s += sn[k];
            out[0] = s * (1.f / BB);
        }
    }
}

extern "C" void kernel_launch(void* const* d_in, const int* in_sizes, int n_in,
                              void* d_out, int out_size, void* d_ws, size_t ws_size,
                              hipStream_t stream) {
    const float* x1  = (const float*)d_in[0];
    const float* x2  = (const float*)d_in[1];
    const float* att1 = (const float*)d_in[2];
    const float* att2 = (const float*)d_in[3];
    const int* ids   = (const int*)d_in[4];
    const int* fp2   = (const int*)d_in[5];
    float* out = (float*)d_out;

    // ws layout (bytes), ~13.6 MB. (R8 finding: the harness poisons the FULL
    // d_ws allocation every iteration (~44 us) regardless of use.)
    unsigned char* w = (unsigned char*)d_ws;
    unsigned short* dbp = (unsigned short*)(w + 0);          // 2*16*393216 = 12,582,912
    int* perm    = (int*)(w + 12582912);                     // 32*2048*4 = 262,144
    int* qcol_s  = (int*)(w + 12845056);                     // 262,144
    int* aqpack  = (int*)(w + 13107200);                     // 262,144
    unsigned int* maxs2enc = (unsigned int*)(w + 13369344);  // 262,144
    float* pnum  = (float*)(w + 13631488);                   // 512
    float* pden  = (float*)(w + 13632000);                   // 512
    unsigned int* done = (unsigned int*)(w + 13632512);      // 4

    prep_fused<<<dim3(552), dim3(256), 0, stream>>>(x1, x2, ids, fp2, dbp,
                                                    perm, qcol_s, aqpack, maxs2enc, done);
    maxscore_mfma<<<dim3(2048), dim3(256), 0, stream>>>(dbp, perm, qcol_s, aqpack, maxs2enc);
    loss_kernel<<<dim3(128), dim3(256), 0, stream>>>(att1, att2, ids, fp2, dbp, maxs2enc,
                                                     pnum, pden, done, out);
}

// Round 12
// 130.990 us; speedup vs baseline: 3.1241x; 1.1266x over previous
//
#include <hip/hip_runtime.h>
#include <stdint.h>

// Problem constants: B=16, C=48, H=W=64, N_CORR=2048
#define BB 16
#define HW 4096
#define NC 2048
#define KB 96            // bytes per column of data (48 bf16)
#define GRPB 12288       // bytes per 128-col group: [6 chunks][128 cols][16B]
#define IMGB 393216      // bytes per (img,b) image: 32 groups

typedef __attribute__((ext_vector_type(8))) __bf16 bf16x8;
typedef __attribute__((ext_vector_type(8))) short short8;
typedef __attribute__((ext_vector_type(4))) float floatx4;

static __device__ __forceinline__ unsigned short f2bf(float f) {
    unsigned u = __builtin_bit_cast(unsigned, f);
    unsigned r = u + 0x7fffu + ((u >> 16) & 1u);    // RNE
    return (unsigned short)(r >> 16);
}

#define GLD16(g, l) __builtin_amdgcn_global_load_lds((const __attribute__((address_space(1))) void*)(g), (__attribute__((address_space(3))) void*)(l), 16, 0, 0)

// ---------------------------------------------------------------------------
// prep_fused (R16 form + done-counter zero): dbp stored TILE-K-MAJOR:
// per (img,b), 32 groups of [chunk k 0..5][col c 0..127][16B].
// ---------------------------------------------------------------------------
__global__ void prep_fused(const float* __restrict__ x1, const float* __restrict__ x2,
                           const int* __restrict__ ids, const int* __restrict__ fp2,
                           unsigned short* __restrict__ dbp,
                           int* __restrict__ perm, int* __restrict__ qcol_s,
                           int* __restrict__ aqpack, unsigned int* __restrict__ maxs2enc,
                           unsigned int* __restrict__ done) {
    __shared__ __align__(16) unsigned char slab[24576 + 4096 + 1024];
    int bid = blockIdx.x, tid = threadIdx.x;
    if (bid < 512) {
        int img = bid >> 8;
        int b = (bid >> 4) & 15;
        int p0 = (bid & 15) * 256;
        int w = tid >> 6, l = tid & 63;
        const float* x = img ? x2 : x1;
        const float* base = x + ((size_t)b * 48 + w * 12) * HW + p0 + 4 * l;
        floatx4 v[12];
        floatx4 ps = {0.f, 0.f, 0.f, 0.f};
#pragma unroll
        for (int cc = 0; cc < 12; ++cc) {
            v[cc] = *(const floatx4*)(base + cc * HW);
#pragma unroll
            for (int q = 0; q < 4; ++q) ps[q] = fmaf(v[cc][q], v[cc][q], ps[q]);
        }
        float* psum = (float*)(slab + 24576);             // [4 waves][256 cols]
        float* rbuf = (float*)(slab + 24576 + 4096);      // [256 cols]
        *(floatx4*)(psum + w * 256 + 4 * l) = ps;
        __syncthreads();
        float s = psum[tid] + psum[256 + tid] + psum[512 + tid] + psum[768 + tid];
        rbuf[tid] = 1.f / fmaxf(sqrtf(s), 1e-12f);
        __syncthreads();
        floatx4 rv = *(const floatx4*)(rbuf + 4 * l);
#pragma unroll
        for (int q = 0; q < 4; ++q) {
            unsigned u[6];
#pragma unroll
            for (int p = 0; p < 6; ++p) {
                u[p] = (unsigned)f2bf(v[2 * p][q] * rv[q]) |
                       ((unsigned)f2bf(v[2 * p + 1][q] * rv[q]) << 16);
            }
            unsigned char* dst = slab + (4 * l + q) * KB + w * 24;  // 8-aligned
            *(uint2*)(dst + 0)  = make_uint2(u[0], u[1]);
            *(uint2*)(dst + 8)  = make_uint2(u[2], u[3]);
            *(uint2*)(dst + 16) = make_uint2(u[4], u[5]);
        }
        __syncthreads();
        // write-out: remap col-major slab -> tile-K-major global, coalesced
        unsigned char* dstb = (unsigned char*)dbp + (size_t)(img * BB + b) * IMGB
                              + (p0 >> 7) * GRPB;
#pragma unroll
        for (int i = 0; i < 6; ++i) {                     // 2 groups * 12288 B
            int L = i * 4096 + tid * 16;
            int g = L / GRPB;                             // 0..1
            int r = L - g * GRPB;
            int k = r >> 11;                              // chunk 0..5
            int c = (r & 2047) >> 4;                      // col 0..127
            *(floatx4*)(dstb + L) = *(const floatx4*)(slab + (g * 128 + c) * KB + k * 16);
        }
    } else if (bid < 544) {
        int* hist = (int*)slab;
        int* base = hist + 64;
        int seg = bid - 512;                      // dir*16 + b
        int dir = seg >> 4, b = seg & 15;
        if (tid < 64) hist[tid] = 0;
        __syncthreads();
#pragma unroll
        for (int k = 0; k < 8; ++k) {
            int n = k * 256 + tid;
            int idv = ids[b * NC + n];
            int i2 = fp2[b * 2 * NC + n];
            int qi = (dir == 0) ? i2 : (idv >> 6);
            atomicAdd(&hist[qi], 1);
        }
        __syncthreads();
        if (tid == 0) {
            int run = 0;
            for (int k = 0; k < 64; ++k) { base[k] = run; run += hist[k]; }
        }
        __syncthreads();
#pragma unroll
        for (int k = 0; k < 8; ++k) {
            int n = k * 256 + tid;
            int idv = ids[b * NC + n];
            int i2 = fp2[b * 2 * NC + n];
            int j2 = fp2[b * 2 * NC + NC + n];
            int qi, qj, qcol;
            if (dir == 0) { qi = i2; qj = j2; qcol = idv; }
            else          { qi = idv >> 6; qj = idv & 63; qcol = i2 * 64 + j2; }
            int slot = atomicAdd(&base[qi], 1);
            perm[seg * NC + slot] = n;
            qcol_s[seg * NC + slot] = qcol;
            aqpack[seg * NC + slot] = (qi << 8) | qj;
        }
    } else {
        int t = (bid - 544) * 256 + tid;          // [0, 2048)
        uint4* p = (uint4*)maxs2enc;              // 16384 uint4 total
        uint4 z = {0u, 0u, 0u, 0u};
#pragma unroll
        for (int k = 0; k < 8; ++k) p[k * 2048 + t] = z;
        if (t == 0) done[0] = 0u;                 // loss tail-block ticket
    }
}

// ---------------------------------------------------------------------------
// maxscore_mfma (R23 = R17 EXACT, the measured champion — 129.3/132.2 us
// totals):  16x16x32 bf16 MFMA, t=2, grid 2048 = 32 seg x 16 mtile x 4 nq,
// tile-K-major dbp, LDS dbuf via global_load_lds (linear both sides),
// STRIDED group walk g = tile*4 + nq (uniform block cost).
// 11 rounds of deviations all regressed or tied:
//   R13 occupancy cap -> spill (383 MB scratch);  R14/R15 layouts -> bank
//   conflict / L2-line amplification;  R18 de-staging -> +9 us (latency);
//   R20 t=4 -> tie;  R21/R22 32x32x16 -> spill / VALU-bound epilogue (57%).
// Remaining budget: ~46 us fixed harness poison + ~42 us latency-bound
// maxscore (no pipe >35%) + ~40 us prep/loss/gaps.
// ---------------------------------------------------------------------------
#define TILEB 12288      // [6][128][16B] == GRPB

static __device__ __forceinline__ void dma_tile(const unsigned char* g, unsigned char* l,
                                                int wave, int lane) {
#pragma unroll
    for (int rr = 0; rr < 3; ++rr)
        GLD16(g + rr * 4096 + wave * 1024 + lane * 16, l + rr * 4096 + wave * 1024);
}

__global__ __launch_bounds__(256, 4) void maxscore_mfma(
    const unsigned short* __restrict__ dbp,
    const int* __restrict__ perm, const int* __restrict__ qcol_s,
    const int* __restrict__ aqpack, unsigned int* __restrict__ maxs2enc) {
    __shared__ __align__(16) unsigned char smem[2 * TILEB];  // 24576 B

    int tid = threadIdx.x, wave = tid >> 6, lane = tid & 63;
    int quad = lane >> 4, cl = lane & 15;
    int gid = blockIdx.x;
    int seg = gid & 31, dir = seg >> 4, b = seg & 15;
    int rest = gid >> 5, mtile = rest & 15, nq = rest >> 4;  // nq in [0,4)
    int qbase = mtile * 128;
    int dbimg = 1 - dir;

    // A-fragments: 16B gathers from tile-K-major dbp (query image = dir)
    const unsigned char* dbQ = (const unsigned char*)dbp + (size_t)(dir * BB + b) * IMGB;
    short8 z8 = {0, 0, 0, 0, 0, 0, 0, 0};
    short8 afr[2][2];
#pragma unroll
    for (int t = 0; t < 2; ++t) {
        int slot = qbase + wave * 32 + t * 16 + cl;       // A[m=lane&15]
        int qc = qcol_s[seg * NC + slot];
        const unsigned char* src = dbQ + (qc >> 7) * GRPB + (qc & 127) * 16;
        afr[t][0] = *(const short8*)(src + quad * 2048);
        // second K=32 MFMA: k' in [16,32) (quads 2,3) is beyond K=48 -> zero A
        afr[t][1] = z8;
        if (quad < 2) afr[t][1] = *(const short8*)(src + (4 + quad) * 2048);
    }
    // Anchors for this lane's C/D rows (row = quad*4+r)
    float qif[2][4], qjc[2][4];
    float cl_f = (float)cl;
#pragma unroll
    for (int t = 0; t < 2; ++t)
#pragma unroll
        for (int r = 0; r < 4; ++r) {
            int slot = qbase + wave * 32 + t * 16 + quad * 4 + r;
            int ap = aqpack[seg * NC + slot];
            qif[t][r] = (float)(ap >> 8);
            qjc[t][r] = (float)(ap & 255) - cl_f;         // qj - lane col offset
        }
    // Wave's sorted qi range (32 consecutive sorted slots)
    int wb = seg * NC + qbase + wave * 32;
    int qimin = __builtin_amdgcn_readfirstlane(aqpack[wb] >> 8);
    int qimax = __builtin_amdgcn_readfirstlane(aqpack[wb + 31] >> 8);

    const unsigned char* dbase = (const unsigned char*)dbp + (size_t)(dbimg * BB + b) * IMGB;
    dma_tile(dbase + (size_t)nq * GRPB, smem, wave, lane);   // prefetch g = 0*4+nq

    const floatx4 zf = {0.f, 0.f, 0.f, 0.f};
    float mx[2][4];
#pragma unroll
    for (int t = 0; t < 2; ++t)
#pragma unroll
        for (int r = 0; r < 4; ++r) mx[t][r] = -1e30f;

    // B-read LDS offsets (K-major): b0 chunk = quad, b1 chunk = 4+(quad&1)
    int b0_off = quad * 2048 + cl * 16;
    int b1_off = (4 + (quad & 1)) * 2048 + cl * 16;

    for (int tile = 0; tile < 8; ++tile) {
        unsigned char* buf = smem + (tile & 1) * TILEB;
        __syncthreads();
        if (tile + 1 < 8)
            dma_tile(dbase + (size_t)((tile + 1) * 4 + nq) * GRPB,
                     smem + ((tile + 1) & 1) * TILEB, wave, lane);
        int mi0 = (tile * 4 + nq) * 2;                    // two db rows per tile
#pragma unroll
        for (int half = 0; half < 2; ++half) {
            int mi = mi0 + half;
            bool active = (mi >= qimin - 4) && (mi <= qimax + 4);   // wave-uniform
            if (active) {
                float mi_f = (float)mi;
                bool rowok[2][4];
#pragma unroll
                for (int t = 0; t < 2; ++t)
#pragma unroll
                    for (int r = 0; r < 4; ++r)
                        rowok[t][r] = fabsf(qif[t][r] - mi_f) > 4.0f;
#pragma unroll
                for (int js = 0; js < 4; ++js) {
                    int sub = half * 4 + js;
                    float jj = (float)(js * 16);
                    short8 b0 = *(const short8*)(buf + b0_off + sub * 256);
                    short8 b1 = *(const short8*)(buf + b1_off + sub * 256);
#pragma unroll
                    for (int t = 0; t < 2; ++t) {
                        floatx4 acc = __builtin_amdgcn_mfma_f32_16x16x32_bf16(
                            __builtin_bit_cast(bf16x8, afr[t][0]),
                            __builtin_bit_cast(bf16x8, b0), zf, 0, 0, 0);
                        acc = __builtin_amdgcn_mfma_f32_16x16x32_bf16(
                            __builtin_bit_cast(bf16x8, afr[t][1]),
                            __builtin_bit_cast(bf16x8, b1), acc, 0, 0, 0);
#pragma unroll
                        for (int r = 0; r < 4; ++r) {
                            float dj = qjc[t][r] - jj;
                            bool ok = rowok[t][r] || (fabsf(dj) > 4.0f);
                            mx[t][r] = ok ? fmaxf(mx[t][r], acc[r]) : mx[t][r];
                        }
                    }
                }
            } else {                                      // all rows allowed: 1 op/elem
#pragma unroll
                for (int js = 0; js < 4; ++js) {
                    int sub = half * 4 + js;
                    short8 b0 = *(const short8*)(buf + b0_off + sub * 256);
                    short8 b1 = *(const short8*)(buf + b1_off + sub * 256);
#pragma unroll
                    for (int t = 0; t < 2; ++t) {
                        floatx4 acc = __builtin_amdgcn_mfma_f32_16x16x32_bf16(
                            __builtin_bit_cast(bf16x8, afr[t][0]),
                            __builtin_bit_cast(bf16x8, b0), zf, 0, 0, 0);
                        acc = __builtin_amdgcn_mfma_f32_16x16x32_bf16(
                            __builtin_bit_cast(bf16x8, afr[t][1]),
                            __builtin_bit_cast(bf16x8, b1), acc, 0, 0, 0);
#pragma unroll
                        for (int r = 0; r < 4; ++r)
                            mx[t][r] = fmaxf(mx[t][r], acc[r]);
                    }
                }
            }
        }
    }

    // reduce max over the 16 lanes of each quad (disjoint col subsets)
#pragma unroll
    for (int t = 0; t < 2; ++t)
#pragma unroll
        for (int r = 0; r < 4; ++r) {
            float v = mx[t][r];
            v = fmaxf(v, __shfl_xor(v, 1, 16));
            v = fmaxf(v, __shfl_xor(v, 2, 16));
            v = fmaxf(v, __shfl_xor(v, 4, 16));
            v = fmaxf(v, __shfl_xor(v, 8, 16));
            mx[t][r] = v;
        }
    if (cl == 0) {
#pragma unroll
        for (int t = 0; t < 2; ++t)
#pragma unroll
            for (int r = 0; r < 4; ++r) {
                int slot = qbase + wave * 32 + t * 16 + quad * 4 + r;
                int orig = perm[seg * NC + slot];
                float v = mx[t][r] + 2.0f;                // > 0: uint-monotone
                atomicMax(&maxs2enc[(size_t)seg * NC + orig],
                          __builtin_bit_cast(unsigned, v));
            }
    }
}

// ---------------------------------------------------------------------------
// loss (R19): pos-distance from tile-K-major dbp bf16 columns, decode/merge
// the two direction maxes, weighted partials — PLUS the former final_kernel,
// executed by the last block to finish (device-scope atomicAdd ticket +
// __threadfence, Guideline-16 pattern).  grid = 128.
// ---------------------------------------------------------------------------
__global__ void loss_kernel(const float* __restrict__ att1, const float* __restrict__ att2,
                            const int* __restrict__ ids, const int* __restrict__ fp2,
                            const unsigned short* __restrict__ dbp,
                            const unsigned int* __restrict__ maxs2enc,
                            float* __restrict__ pnum, float* __restrict__ pden,
                            unsigned int* __restrict__ done, float* __restrict__ out) {
    int b = blockIdx.x >> 3, chunk = blockIdx.x & 7;
    int tid = threadIdx.x;
    int n = chunk * 256 + tid;
    int idv = ids[b * NC + n];
    int i2 = fp2[b * 2 * NC + n], j2 = fp2[b * 2 * NC + NC + n];
    int c2 = i2 * 64 + j2;
    const unsigned char* a4 = (const unsigned char*)dbp + (size_t)(0 * BB + b) * IMGB
                              + (idv >> 7) * GRPB + (idv & 127) * 16;
    const unsigned char* b4 = (const unsigned char*)dbp + (size_t)(1 * BB + b) * IMGB
                              + (c2 >> 7) * GRPB + (c2 & 127) * 16;
    float dot = 0.f;
#pragma unroll
    for (int i = 0; i < 6; ++i) {                         // 6 chunks x 16 B
        uint4 xa = *(const uint4*)(a4 + i * 2048);
        uint4 xb = *(const uint4*)(b4 + i * 2048);
        const unsigned* xu = (const unsigned*)&xa;
        const unsigned* yu = (const unsigned*)&xb;
#pragma unroll
        for (int w = 0; w < 4; ++w) {
            float xl = __builtin_bit_cast(float, xu[w] << 16);
            float xh = __builtin_bit_cast(float, xu[w] & 0xffff0000u);
            float yl = __builtin_bit_cast(float, yu[w] << 16);
            float yh = __builtin_bit_cast(float, yu[w] & 0xffff0000u);
            dot = fmaf(xl, yl, fmaf(xh, yh, dot));
        }
    }
    float m0 = __builtin_bit_cast(float, maxs2enc[(size_t)(0 * BB + b) * NC + n]) - 2.0f;
    float m1 = __builtin_bit_cast(float, maxs2enc[(size_t)(1 * BB + b) * NC + n]) - 2.0f;
    float ms = fmaxf(m0, m1);
    float diff = (2.f - 2.f * dot) - (2.f - 2.f * ms);
    float w = att1[b * HW + idv] * att2[b * HW + c2];
    float num = w * fmaxf(0.f, 1.f + diff);
    float den = w;
    __shared__ float sn[256], sd[256];
    __shared__ int islast;
    sn[tid] = num; sd[tid] = den;
    __syncthreads();
    for (int s = 128; s > 0; s >>= 1) {
        if (tid < s) { sn[tid] += sn[tid + s]; sd[tid] += sd[tid + s]; }
        __syncthreads();
    }
    if (tid == 0) {
        pnum[blockIdx.x] = sn[0];
        pden[blockIdx.x] = sd[0];
        __threadfence();                                  // release partials
        unsigned t = atomicAdd(done, 1u);
        islast = (t == 127u);
    }
    __syncthreads();
    if (islast) {
        __threadfence();                                  // acquire partials
        if (tid < 16) {
            float nacc = 0.f, dacc = 0.f;
#pragma unroll
            for (int c = 0; c < 8; ++c) {
                nacc += pnum[tid * 8 + c];
                dacc += pden[tid * 8 + c];
            }
            sn[tid] = nacc / dacc;
        }
        __syncthreads();
        if (tid == 0) {
            float s = 0.f;
#pragma unroll
            for (int k = 0; k < 16; ++k) s += sn[k];
            out[0] = s * (1.f / BB);
        }
    }
}

extern "C" void kernel_launch(void* const* d_in, const int* in_sizes, int n_in,
                              void* d_out, int out_size, void* d_ws, size_t ws_size,
                              hipStream_t stream) {
    const float* x1  = (const float*)d_in[0];
    const float* x2  = (const float*)d_in[1];
    const float* att1 = (const float*)d_in[2];
    const float* att2 = (const float*)d_in[3];
    const int* ids   = (const int*)d_in[4];
    const int* fp2   = (const int*)d_in[5];
    float* out = (float*)d_out;

    // ws layout (bytes), ~13.6 MB. (R8 finding: the harness poisons the FULL
    // d_ws allocation every iteration (~44 us) regardless of use.)
    unsigned char* w = (unsigned char*)d_ws;
    unsigned short* dbp = (unsigned short*)(w + 0);          // 2*16*393216 = 12,582,912
    int* perm    = (int*)(w + 12582912);                     // 32*2048*4 = 262,144
    int* qcol_s  = (int*)(w + 12845056);                     // 262,144
    int* aqpack  = (int*)(w + 13107200);                     // 262,144
    unsigned int* maxs2enc = (unsigned int*)(w + 13369344);  // 262,144
    float* pnum  = (float*)(w + 13631488);                   // 512
    float* pden  = (float*)(w + 13632000);                   // 512
    unsigned int* done = (unsigned int*)(w + 13632512);      // 4

    prep_fused<<<dim3(552), dim3(256), 0, stream>>>(x1, x2, ids, fp2, dbp,
                                                    perm, qcol_s, aqpack, maxs2enc, done);
    maxscore_mfma<<<dim3(2048), dim3(256), 0, stream>>>(dbp, perm, qcol_s, aqpack, maxs2enc);
    loss_kernel<<<dim3(128), dim3(256), 0, stream>>>(att1, att2, ids, fp2, dbp, maxs2enc,
                                                     pnum, pden, done, out);
}